// Round 1
// baseline (432.177 us; speedup 1.0000x reference)
//
#include <hip/hip_runtime.h>
#include <math.h>

// ---------------------------------------------------------------------------
// GCN forward: gcn_norm (self-loops) -> [GEMM + CSR-aggregate + bias + relu] x2
//              -> segment_max pool (fused into agg2 via int atomicMax)
//              -> small FC.
// All fp32. CSR is rebuilt on-device every call (ws is re-poisoned).
// ---------------------------------------------------------------------------

__global__ __launch_bounds__(256) void k_zero(int* __restrict__ cnt, int* __restrict__ pool,
                                              int n1, int n2) {
    int i = blockIdx.x * 256 + threadIdx.x;
    if (i < n1) cnt[i] = 0;
    if (i < n2) pool[i] = 0;
}

__global__ __launch_bounds__(256) void k_count(const int* __restrict__ ei, int* __restrict__ cnt,
                                               int E) {
    int e = blockIdx.x * 256 + threadIdx.x;
    if (e < E) atomicAdd(&cnt[ei[E + e]], 1);
}

__global__ __launch_bounds__(256) void k_dis(const int* __restrict__ cnt, float* __restrict__ dis,
                                             int N) {
    int v = blockIdx.x * 256 + threadIdx.x;
    if (v < N) dis[v] = 1.0f / sqrtf((float)(cnt[v] + 1));  // +1 self-loop
}

// block-local exclusive scan (1024/block) -> rowptr (local), bsum[block] = total
__global__ __launch_bounds__(1024) void k_scan_block(const int* __restrict__ cnt,
                                                     int* __restrict__ rowptr,
                                                     int* __restrict__ bsum, int N) {
    __shared__ int lds[1024];
    int t = threadIdx.x;
    int i = blockIdx.x * 1024 + t;
    int val = (i < N) ? cnt[i] : 0;
    lds[t] = val;
    __syncthreads();
    for (int off = 1; off < 1024; off <<= 1) {
        int u = (t >= off) ? lds[t - off] : 0;
        __syncthreads();
        lds[t] += u;
        __syncthreads();
    }
    if (i < N) rowptr[i] = lds[t] - val;  // exclusive within block
    if (t == 1023) bsum[blockIdx.x] = lds[1023];
}

__global__ __launch_bounds__(1024) void k_scan_tot(const int* __restrict__ bsum,
                                                   int* __restrict__ bsum2, int nb) {
    __shared__ int lds[1024];
    int t = threadIdx.x;
    int val = (t < nb) ? bsum[t] : 0;
    lds[t] = val;
    __syncthreads();
    for (int off = 1; off < 1024; off <<= 1) {
        int u = (t >= off) ? lds[t - off] : 0;
        __syncthreads();
        lds[t] += u;
        __syncthreads();
    }
    if (t < nb) bsum2[t] = lds[t] - val;  // exclusive
}

__global__ __launch_bounds__(256) void k_scan_add(int* __restrict__ rowptr, int* __restrict__ cursor,
                                                  const int* __restrict__ bsum2, int N, int E) {
    int i = blockIdx.x * 256 + threadIdx.x;
    if (i < N) {
        int r = rowptr[i] + bsum2[i >> 10];
        rowptr[i] = r;
        cursor[i] = r;
    }
    if (i == 0) rowptr[N] = E;
}

__global__ __launch_bounds__(256) void k_fill(const int* __restrict__ ei,
                                              const float* __restrict__ dis,
                                              int* __restrict__ cursor,
                                              int* __restrict__ csr_src,
                                              float* __restrict__ csr_w, int E) {
    int e = blockIdx.x * 256 + threadIdx.x;
    if (e >= E) return;
    int r = ei[e];
    int c = ei[E + e];
    int p = atomicAdd(&cursor[c], 1);
    csr_src[p] = r;
    csr_w[p] = dis[r] * dis[c];
}

// ---------------------------------------------------------------------------
// fp32 GEMM: C[M x NOUT] = A[M x KDIM] @ W[KDIM x NOUT]
// BM=64 rows/block, BK=32 K-chunk, 256 threads. Thread computes 4 rows x
// (4*NGRP) cols: cols tx*4..+3 and (64+tx*4)..+3 when NOUT=128.
// As stored transposed [k][m] (pad +4) so the inner read is an aligned float4.
// ---------------------------------------------------------------------------
template <int KDIM, int NOUT>
__global__ __launch_bounds__(256) void k_gemm(const float* __restrict__ A,
                                              const float* __restrict__ W,
                                              float* __restrict__ C, int M) {
    constexpr int BM = 64, BK = 32;
    constexpr int NGRP = NOUT / 64;  // 2 for 128, 1 for 64
    __shared__ float As[BK][BM + 4];
    __shared__ float Ws[BK][NOUT];

    const int t = threadIdx.x;
    const int tx = t & 15;   // col group
    const int ty = t >> 4;   // row group (4 rows)
    const int row0 = blockIdx.x * BM;

    float acc[4][4 * NGRP];
#pragma unroll
    for (int r = 0; r < 4; r++)
#pragma unroll
        for (int c = 0; c < 4 * NGRP; c++) acc[r][c] = 0.f;

    for (int kc = 0; kc < KDIM; kc += BK) {
        // A tile: 64 rows x 32 k = 512 float4 slots, 2 per thread; store transposed
#pragma unroll
        for (int i = 0; i < 2; i++) {
            int s = t * 2 + i;
            int m = s >> 3;
            int kq = s & 7;
            int r = row0 + m;
            float4 v = make_float4(0.f, 0.f, 0.f, 0.f);
            if (r < M) v = *(const float4*)&A[(size_t)r * KDIM + kc + kq * 4];
            As[kq * 4 + 0][m] = v.x;
            As[kq * 4 + 1][m] = v.y;
            As[kq * 4 + 2][m] = v.z;
            As[kq * 4 + 3][m] = v.w;
        }
        // W tile: BK x NOUT floats
        constexpr int WLOADS = (BK * NOUT / 4) / 256;
#pragma unroll
        for (int i = 0; i < WLOADS; i++) {
            int s = t + i * 256;
            int k = s / (NOUT / 4);
            int c4 = s % (NOUT / 4);
            *(float4*)&Ws[k][c4 * 4] = *(const float4*)&W[(size_t)(kc + k) * NOUT + c4 * 4];
        }
        __syncthreads();

#pragma unroll
        for (int k = 0; k < BK; k++) {
            float4 a = *(const float4*)&As[k][ty * 4];
            float4 w0 = *(const float4*)&Ws[k][tx * 4];
            float4 w1;
            if (NGRP == 2) w1 = *(const float4*)&Ws[k][64 + tx * 4];
            const float* ap = (const float*)&a;
            const float* w0p = (const float*)&w0;
            const float* w1p = (const float*)&w1;
#pragma unroll
            for (int r = 0; r < 4; r++) {
#pragma unroll
                for (int c = 0; c < 4; c++) {
                    acc[r][c] += ap[r] * w0p[c];
                    if (NGRP == 2) acc[r][4 + c] += ap[r] * w1p[c];
                }
            }
        }
        __syncthreads();
    }

#pragma unroll
    for (int r = 0; r < 4; r++) {
        int rr = row0 + ty * 4 + r;
        if (rr < M) {
            float4 o0 = make_float4(acc[r][0], acc[r][1], acc[r][2], acc[r][3]);
            *(float4*)&C[(size_t)rr * NOUT + tx * 4] = o0;
            if (NGRP == 2) {
                float4 o1 = make_float4(acc[r][4], acc[r][5], acc[r][6], acc[r][7]);
                *(float4*)&C[(size_t)rr * NOUT + 64 + tx * 4] = o1;
            }
        }
    }
}

// one wave per node, 128 features as float2/lane: out = relu(agg + b)
__global__ __launch_bounds__(256) void k_agg1(const float* __restrict__ h,
                                              const int* __restrict__ rowptr,
                                              const int* __restrict__ src,
                                              const float* __restrict__ wgt,
                                              const float* __restrict__ dis,
                                              const float* __restrict__ b,
                                              float* __restrict__ out, int N) {
    int wave = (blockIdx.x * 256 + threadIdx.x) >> 6;
    int lane = threadIdx.x & 63;
    if (wave >= N) return;
    const int v = wave;
    float d = dis[v];
    float ds2 = d * d;
    float2 hv = *(const float2*)&h[(size_t)v * 128 + lane * 2];
    float ax = ds2 * hv.x, ay = ds2 * hv.y;
    int s0 = rowptr[v], s1 = rowptr[v + 1];
    for (int j = s0; j < s1; ++j) {
        int u = src[j];
        float w = wgt[j];
        float2 hu = *(const float2*)&h[(size_t)u * 128 + lane * 2];
        ax += w * hu.x;
        ay += w * hu.y;
    }
    float2 bb = *(const float2*)&b[lane * 2];
    float2 o;
    o.x = fmaxf(ax + bb.x, 0.f);
    o.y = fmaxf(ay + bb.y, 0.f);
    *(float2*)&out[(size_t)v * 128 + lane * 2] = o;
}

// one wave per node, 64 features scalar/lane; fused bias+relu+graph max-pool
__global__ __launch_bounds__(256) void k_agg2_pool(const float* __restrict__ h,
                                                   const int* __restrict__ rowptr,
                                                   const int* __restrict__ src,
                                                   const float* __restrict__ wgt,
                                                   const float* __restrict__ dis,
                                                   const float* __restrict__ b,
                                                   const int* __restrict__ batch,
                                                   float* __restrict__ pool, int N) {
    int wave = (blockIdx.x * 256 + threadIdx.x) >> 6;
    int lane = threadIdx.x & 63;
    if (wave >= N) return;
    const int v = wave;
    float d = dis[v];
    float ds2 = d * d;
    float acc = ds2 * h[(size_t)v * 64 + lane];
    int s0 = rowptr[v], s1 = rowptr[v + 1];
    for (int j = s0; j < s1; ++j) {
        int u = src[j];
        float w = wgt[j];
        acc += w * h[(size_t)u * 64 + lane];
    }
    float val = fmaxf(acc + b[lane], 0.f);
    int g = batch[v];
    // val >= 0 so float bits order as signed ints; pool zero-initialized.
    atomicMax((int*)&pool[(size_t)g * 64 + lane], __float_as_int(val));
}

__global__ __launch_bounds__(256) void k_fc(const float* __restrict__ pool,
                                            const float* __restrict__ Wfc,
                                            const float* __restrict__ bfc,
                                            float* __restrict__ out, int G) {
    int t = blockIdx.x * 256 + threadIdx.x;
    if (t >= G * 10) return;
    int g = t / 10, o = t % 10;
    float acc = bfc[o];
#pragma unroll
    for (int f = 0; f < 64; f++) acc += pool[g * 64 + f] * Wfc[f * 10 + o];
    out[t] = acc;
}

extern "C" void kernel_launch(void* const* d_in, const int* in_sizes, int n_in,
                              void* d_out, int out_size, void* d_ws, size_t ws_size,
                              hipStream_t stream) {
    const float* x   = (const float*)d_in[0];
    const int*   ei  = (const int*)d_in[1];
    const int*   bat = (const int*)d_in[2];
    const float* W1  = (const float*)d_in[3];
    const float* b1  = (const float*)d_in[4];
    const float* W2  = (const float*)d_in[5];
    const float* b2  = (const float*)d_in[6];
    const float* Wfc = (const float*)d_in[7];
    const float* bfc = (const float*)d_in[8];
    float* out = (float*)d_out;

    const int N = in_sizes[2];          // 50000
    const int E = in_sizes[1] / 2;      // 800000
    const int G = out_size / 10;        // 128

    // workspace layout (256B aligned)
    char* ws = (char*)d_ws;
    size_t off = 0;
    auto alloc = [&](size_t bytes) -> char* {
        char* p = ws + off;
        off = (off + bytes + 255) & ~(size_t)255;
        return p;
    };
    int*   cnt     = (int*)alloc((size_t)N * 4);
    float* dis     = (float*)alloc((size_t)N * 4);
    int*   rowptr  = (int*)alloc((size_t)(N + 1) * 4);
    int*   cursor  = (int*)alloc((size_t)N * 4);
    int*   bsum    = (int*)alloc(1024 * 4);
    int*   bsum2   = (int*)alloc(1024 * 4);
    int*   csr_src = (int*)alloc((size_t)E * 4);
    float* csr_w   = (float*)alloc((size_t)E * 4);
    float* h       = (float*)alloc((size_t)N * 128 * 4);  // h1, reused as h2
    float* a1      = (float*)alloc((size_t)N * 128 * 4);
    float* pool    = (float*)alloc((size_t)G * 64 * 4);
    (void)ws_size; (void)n_in;

    const int nb = (N + 1023) / 1024;

    // ---- gcn_norm + CSR build ----
    {
        int zmax = N > G * 64 ? N : G * 64;
        k_zero<<<(zmax + 255) / 256, 256, 0, stream>>>(cnt, (int*)pool, N, G * 64);
    }
    k_count<<<(E + 255) / 256, 256, 0, stream>>>(ei, cnt, E);
    k_dis<<<(N + 255) / 256, 256, 0, stream>>>(cnt, dis, N);
    k_scan_block<<<nb, 1024, 0, stream>>>(cnt, rowptr, bsum, N);
    k_scan_tot<<<1, 1024, 0, stream>>>(bsum, bsum2, nb);
    k_scan_add<<<(N + 255) / 256, 256, 0, stream>>>(rowptr, cursor, bsum2, N, E);
    k_fill<<<(E + 255) / 256, 256, 0, stream>>>(ei, dis, cursor, csr_src, csr_w, E);

    // ---- layer 1 ----
    k_gemm<256, 128><<<(N + 63) / 64, 256, 0, stream>>>(x, W1, h, N);
    k_agg1<<<(N * 64 + 255) / 256, 256, 0, stream>>>(h, rowptr, csr_src, csr_w, dis, b1, a1, N);

    // ---- layer 2 (h reused as h2) ----
    k_gemm<128, 64><<<(N + 63) / 64, 256, 0, stream>>>(a1, W2, h, N);
    k_agg2_pool<<<(N * 64 + 255) / 256, 256, 0, stream>>>(h, rowptr, csr_src, csr_w, dis, b2,
                                                          bat, pool, N);

    // ---- FC head ----
    k_fc<<<(G * 10 + 255) / 256, 256, 0, stream>>>(pool, Wfc, bfc, out, G);
}

// Round 3
// 373.451 us; speedup vs baseline: 1.1573x; 1.1573x over previous
//
#include <hip/hip_runtime.h>
#include <math.h>

// ---------------------------------------------------------------------------
// GCN forward: gcn_norm (self-loops) -> [GEMM + CSR-aggregate + bias + relu] x2
//              -> segment_max pool (fused into agg2 via int atomicMax)
//              -> small FC.
// All fp32. CSR rebuilt on-device every call (ws is re-poisoned).
// R2: packed 8B CSR entries + 8x unrolled predicated gather loop (MLP fix).
// (Resubmitted unchanged after GPU acquisition timeout.)
// ---------------------------------------------------------------------------

__global__ __launch_bounds__(256) void k_zero(int* __restrict__ cnt, int* __restrict__ pool,
                                              int n1, int n2) {
    int i = blockIdx.x * 256 + threadIdx.x;
    if (i < n1) cnt[i] = 0;
    if (i < n2) pool[i] = 0;
}

__global__ __launch_bounds__(256) void k_count(const int* __restrict__ ei, int* __restrict__ cnt,
                                               int E) {
    int e = blockIdx.x * 256 + threadIdx.x;
    if (e < E) atomicAdd(&cnt[ei[E + e]], 1);
}

__global__ __launch_bounds__(256) void k_dis(const int* __restrict__ cnt, float* __restrict__ dis,
                                             int N) {
    int v = blockIdx.x * 256 + threadIdx.x;
    if (v < N) dis[v] = 1.0f / sqrtf((float)(cnt[v] + 1));  // +1 self-loop
}

// block-local exclusive scan (1024/block) -> rowptr (local), bsum[block] = total
__global__ __launch_bounds__(1024) void k_scan_block(const int* __restrict__ cnt,
                                                     int* __restrict__ rowptr,
                                                     int* __restrict__ bsum, int N) {
    __shared__ int lds[1024];
    int t = threadIdx.x;
    int i = blockIdx.x * 1024 + t;
    int val = (i < N) ? cnt[i] : 0;
    lds[t] = val;
    __syncthreads();
    for (int off = 1; off < 1024; off <<= 1) {
        int u = (t >= off) ? lds[t - off] : 0;
        __syncthreads();
        lds[t] += u;
        __syncthreads();
    }
    if (i < N) rowptr[i] = lds[t] - val;  // exclusive within block
    if (t == 1023) bsum[blockIdx.x] = lds[1023];
}

__global__ __launch_bounds__(1024) void k_scan_tot(const int* __restrict__ bsum,
                                                   int* __restrict__ bsum2, int nb) {
    __shared__ int lds[1024];
    int t = threadIdx.x;
    int val = (t < nb) ? bsum[t] : 0;
    lds[t] = val;
    __syncthreads();
    for (int off = 1; off < 1024; off <<= 1) {
        int u = (t >= off) ? lds[t - off] : 0;
        __syncthreads();
        lds[t] += u;
        __syncthreads();
    }
    if (t < nb) bsum2[t] = lds[t] - val;  // exclusive
}

__global__ __launch_bounds__(256) void k_scan_add(int* __restrict__ rowptr, int* __restrict__ cursor,
                                                  const int* __restrict__ bsum2, int N, int E) {
    int i = blockIdx.x * 256 + threadIdx.x;
    if (i < N) {
        int r = rowptr[i] + bsum2[i >> 10];
        rowptr[i] = r;
        cursor[i] = r;
    }
    if (i == 0) rowptr[N] = E;
}

// packed CSR entry: .x = src index (int bits), .y = edge weight
__global__ __launch_bounds__(256) void k_fill(const int* __restrict__ ei,
                                              const float* __restrict__ dis,
                                              int* __restrict__ cursor,
                                              float2* __restrict__ csr, int E) {
    int e = blockIdx.x * 256 + threadIdx.x;
    if (e >= E) return;
    int r = ei[e];
    int c = ei[E + e];
    int p = atomicAdd(&cursor[c], 1);
    csr[p] = make_float2(__int_as_float(r), dis[r] * dis[c]);
}

// ---------------------------------------------------------------------------
// fp32 GEMM: C[M x NOUT] = A[M x KDIM] @ W[KDIM x NOUT]
// ---------------------------------------------------------------------------
template <int KDIM, int NOUT>
__global__ __launch_bounds__(256) void k_gemm(const float* __restrict__ A,
                                              const float* __restrict__ W,
                                              float* __restrict__ C, int M) {
    constexpr int BM = 64, BK = 32;
    constexpr int NGRP = NOUT / 64;  // 2 for 128, 1 for 64
    __shared__ float As[BK][BM + 4];
    __shared__ float Ws[BK][NOUT];

    const int t = threadIdx.x;
    const int tx = t & 15;   // col group
    const int ty = t >> 4;   // row group (4 rows)
    const int row0 = blockIdx.x * BM;

    float acc[4][4 * NGRP];
#pragma unroll
    for (int r = 0; r < 4; r++)
#pragma unroll
        for (int c = 0; c < 4 * NGRP; c++) acc[r][c] = 0.f;

    for (int kc = 0; kc < KDIM; kc += BK) {
#pragma unroll
        for (int i = 0; i < 2; i++) {
            int s = t * 2 + i;
            int m = s >> 3;
            int kq = s & 7;
            int r = row0 + m;
            float4 v = make_float4(0.f, 0.f, 0.f, 0.f);
            if (r < M) v = *(const float4*)&A[(size_t)r * KDIM + kc + kq * 4];
            As[kq * 4 + 0][m] = v.x;
            As[kq * 4 + 1][m] = v.y;
            As[kq * 4 + 2][m] = v.z;
            As[kq * 4 + 3][m] = v.w;
        }
        constexpr int WLOADS = (BK * NOUT / 4) / 256;
#pragma unroll
        for (int i = 0; i < WLOADS; i++) {
            int s = t + i * 256;
            int k = s / (NOUT / 4);
            int c4 = s % (NOUT / 4);
            *(float4*)&Ws[k][c4 * 4] = *(const float4*)&W[(size_t)(kc + k) * NOUT + c4 * 4];
        }
        __syncthreads();

#pragma unroll
        for (int k = 0; k < BK; k++) {
            float4 a = *(const float4*)&As[k][ty * 4];
            float4 w0 = *(const float4*)&Ws[k][tx * 4];
            float4 w1;
            if (NGRP == 2) w1 = *(const float4*)&Ws[k][64 + tx * 4];
            const float* ap = (const float*)&a;
            const float* w0p = (const float*)&w0;
            const float* w1p = (const float*)&w1;
#pragma unroll
            for (int r = 0; r < 4; r++) {
#pragma unroll
                for (int c = 0; c < 4; c++) {
                    acc[r][c] += ap[r] * w0p[c];
                    if (NGRP == 2) acc[r][4 + c] += ap[r] * w1p[c];
                }
            }
        }
        __syncthreads();
    }

#pragma unroll
    for (int r = 0; r < 4; r++) {
        int rr = row0 + ty * 4 + r;
        if (rr < M) {
            float4 o0 = make_float4(acc[r][0], acc[r][1], acc[r][2], acc[r][3]);
            *(float4*)&C[(size_t)rr * NOUT + tx * 4] = o0;
            if (NGRP == 2) {
                float4 o1 = make_float4(acc[r][4], acc[r][5], acc[r][6], acc[r][7]);
                *(float4*)&C[(size_t)rr * NOUT + 64 + tx * 4] = o1;
            }
        }
    }
}

// one wave per node, 128 features as float2/lane: out = relu(agg + b)
// 8x unrolled, index-clamped (no serial tail) -> 8 gathers in flight.
__global__ __launch_bounds__(256) void k_agg1(const float* __restrict__ h,
                                              const int* __restrict__ rowptr,
                                              const float2* __restrict__ csr,
                                              const float* __restrict__ dis,
                                              const float* __restrict__ b,
                                              float* __restrict__ out, int N) {
    int wave = (blockIdx.x * 256 + threadIdx.x) >> 6;
    int lane = threadIdx.x & 63;
    if (wave >= N) return;
    const int v = wave;
    const float2* hp = (const float2*)h;  // row stride = 64 float2
    float d = dis[v];
    float ds2 = d * d;
    float2 hv = hp[(size_t)v * 64 + lane];
    float ax = ds2 * hv.x, ay = ds2 * hv.y;
    int s0 = rowptr[v], s1 = rowptr[v + 1];
    for (int j = s0; j < s1; j += 8) {
        int   uu[8];
        float ww[8];
#pragma unroll
        for (int q = 0; q < 8; q++) {
            int jj = j + q;
            bool ok = jj < s1;
            float2 e = csr[ok ? jj : s0];
            uu[q] = __float_as_int(e.x);
            ww[q] = ok ? e.y : 0.f;
        }
        float2 g[8];
#pragma unroll
        for (int q = 0; q < 8; q++) g[q] = hp[(size_t)uu[q] * 64 + lane];
#pragma unroll
        for (int q = 0; q < 8; q++) {
            ax += ww[q] * g[q].x;
            ay += ww[q] * g[q].y;
        }
    }
    float2 bb = *(const float2*)&b[lane * 2];
    float2 o;
    o.x = fmaxf(ax + bb.x, 0.f);
    o.y = fmaxf(ay + bb.y, 0.f);
    *(float2*)&out[(size_t)v * 128 + lane * 2] = o;
}

// one wave per node, 64 features scalar/lane; fused bias+relu+graph max-pool
__global__ __launch_bounds__(256) void k_agg2_pool(const float* __restrict__ h,
                                                   const int* __restrict__ rowptr,
                                                   const float2* __restrict__ csr,
                                                   const float* __restrict__ dis,
                                                   const float* __restrict__ b,
                                                   const int* __restrict__ batch,
                                                   float* __restrict__ pool, int N) {
    int wave = (blockIdx.x * 256 + threadIdx.x) >> 6;
    int lane = threadIdx.x & 63;
    if (wave >= N) return;
    const int v = wave;
    float d = dis[v];
    float ds2 = d * d;
    float acc = ds2 * h[(size_t)v * 64 + lane];
    int s0 = rowptr[v], s1 = rowptr[v + 1];
    for (int j = s0; j < s1; j += 8) {
        int   uu[8];
        float ww[8];
#pragma unroll
        for (int q = 0; q < 8; q++) {
            int jj = j + q;
            bool ok = jj < s1;
            float2 e = csr[ok ? jj : s0];
            uu[q] = __float_as_int(e.x);
            ww[q] = ok ? e.y : 0.f;
        }
        float g[8];
#pragma unroll
        for (int q = 0; q < 8; q++) g[q] = h[(size_t)uu[q] * 64 + lane];
#pragma unroll
        for (int q = 0; q < 8; q++) acc += ww[q] * g[q];
    }
    float val = fmaxf(acc + b[lane], 0.f);
    int g = batch[v];
    // val >= 0 so float bits order as signed ints; pool zero-initialized.
    atomicMax((int*)&pool[(size_t)g * 64 + lane], __float_as_int(val));
}

__global__ __launch_bounds__(256) void k_fc(const float* __restrict__ pool,
                                            const float* __restrict__ Wfc,
                                            const float* __restrict__ bfc,
                                            float* __restrict__ out, int G) {
    int t = blockIdx.x * 256 + threadIdx.x;
    if (t >= G * 10) return;
    int g = t / 10, o = t % 10;
    float acc = bfc[o];
#pragma unroll
    for (int f = 0; f < 64; f++) acc += pool[g * 64 + f] * Wfc[f * 10 + o];
    out[t] = acc;
}

extern "C" void kernel_launch(void* const* d_in, const int* in_sizes, int n_in,
                              void* d_out, int out_size, void* d_ws, size_t ws_size,
                              hipStream_t stream) {
    const float* x   = (const float*)d_in[0];
    const int*   ei  = (const int*)d_in[1];
    const int*   bat = (const int*)d_in[2];
    const float* W1  = (const float*)d_in[3];
    const float* b1  = (const float*)d_in[4];
    const float* W2  = (const float*)d_in[5];
    const float* b2  = (const float*)d_in[6];
    const float* Wfc = (const float*)d_in[7];
    const float* bfc = (const float*)d_in[8];
    float* out = (float*)d_out;

    const int N = in_sizes[2];          // 50000
    const int E = in_sizes[1] / 2;      // 800000
    const int G = out_size / 10;        // 128

    // workspace layout (256B aligned)
    char* ws = (char*)d_ws;
    size_t off = 0;
    auto alloc = [&](size_t bytes) -> char* {
        char* p = ws + off;
        off = (off + bytes + 255) & ~(size_t)255;
        return p;
    };
    int*    cnt    = (int*)alloc((size_t)N * 4);
    float*  dis    = (float*)alloc((size_t)N * 4);
    int*    rowptr = (int*)alloc((size_t)(N + 1) * 4);
    int*    cursor = (int*)alloc((size_t)N * 4);
    int*    bsum   = (int*)alloc(1024 * 4);
    int*    bsum2  = (int*)alloc(1024 * 4);
    float2* csr    = (float2*)alloc((size_t)E * 8);
    float*  h      = (float*)alloc((size_t)N * 128 * 4);  // h1, reused as h2
    float*  a1     = (float*)alloc((size_t)N * 128 * 4);
    float*  pool   = (float*)alloc((size_t)G * 64 * 4);
    (void)ws_size; (void)n_in;

    const int nb = (N + 1023) / 1024;

    // ---- gcn_norm + CSR build ----
    {
        int zmax = N > G * 64 ? N : G * 64;
        k_zero<<<(zmax + 255) / 256, 256, 0, stream>>>(cnt, (int*)pool, N, G * 64);
    }
    k_count<<<(E + 255) / 256, 256, 0, stream>>>(ei, cnt, E);
    k_dis<<<(N + 255) / 256, 256, 0, stream>>>(cnt, dis, N);
    k_scan_block<<<nb, 1024, 0, stream>>>(cnt, rowptr, bsum, N);
    k_scan_tot<<<1, 1024, 0, stream>>>(bsum, bsum2, nb);
    k_scan_add<<<(N + 255) / 256, 256, 0, stream>>>(rowptr, cursor, bsum2, N, E);
    k_fill<<<(E + 255) / 256, 256, 0, stream>>>(ei, dis, cursor, csr, E);

    // ---- layer 1 ----
    k_gemm<256, 128><<<(N + 63) / 64, 256, 0, stream>>>(x, W1, h, N);
    k_agg1<<<(N * 64 + 255) / 256, 256, 0, stream>>>(h, rowptr, csr, dis, b1, a1, N);

    // ---- layer 2 (h reused as h2) ----
    k_gemm<128, 64><<<(N + 63) / 64, 256, 0, stream>>>(a1, W2, h, N);
    k_agg2_pool<<<(N * 64 + 255) / 256, 256, 0, stream>>>(h, rowptr, csr, dis, b2, bat, pool, N);

    // ---- FC head ----
    k_fc<<<(G * 10 + 255) / 256, 256, 0, stream>>>(pool, Wfc, bfc, out, G);
}